// Round 1
// baseline (145.118 us; speedup 1.0000x reference)
//
#include <hip/hip_runtime.h>
#include <hip/hip_bf16.h>

typedef __bf16 bf16x8 __attribute__((ext_vector_type(8)));
typedef float  f32x4  __attribute__((ext_vector_type(4)));

#define MFMA16(a, b, c) __builtin_amdgcn_mfma_f32_16x16x32_bf16(a, b, c, 0, 0, 0)

static __device__ __forceinline__ unsigned short bf16_bits(__bf16 v) {
    union { __bf16 b; unsigned short u; } x; x.b = v; return x.u;
}
static __device__ __forceinline__ f32x4 zero4() {
    f32x4 z = {0.f, 0.f, 0.f, 0.f}; return z;
}

// ---------------------------------------------------------------------------
// K0a: G[c][j] = sum_d Wq[c][d] * rpe[j][d]   (c<512, j<64; only j<50 used)
// ---------------------------------------------------------------------------
__global__ void g_build_kernel(const float* __restrict__ Wq,
                               const float* __restrict__ rpe,
                               float* __restrict__ G) {
    int gid = blockIdx.x * 256 + threadIdx.x;   // 32768 total
    int c = gid >> 6, j = gid & 63;
    const f32x4* wp = (const f32x4*)(Wq + c * 64);
    const f32x4* rp = (const f32x4*)(rpe + j * 64);
    float acc = 0.f;
#pragma unroll
    for (int i = 0; i < 16; i++) {
        f32x4 a = wp[i], b = rp[i];
        acc += a.x * b.x + a.y * b.y + a.z * b.z + a.w * b.w;
    }
    G[c * 64 + j] = acc;
}

// ---------------------------------------------------------------------------
// K0b: WT_hi/lo[n][k] = split(bf16) of augmented-W^T; n: [Wq|Wk|Wv|G] cols
// ---------------------------------------------------------------------------
__global__ void wt_build_kernel(const float* __restrict__ Wq,
                                const float* __restrict__ Wk,
                                const float* __restrict__ Wv,
                                const float* __restrict__ G,
                                __bf16* __restrict__ WT_hi,
                                __bf16* __restrict__ WT_lo) {
    int n = blockIdx.x;          // 0..255
    const float* src; int nc;
    if (n < 64)       { src = Wq; nc = n; }
    else if (n < 128) { src = Wk; nc = n - 64; }
    else if (n < 192) { src = Wv; nc = n - 128; }
    else              { src = G;  nc = n - 192; }
    int k = threadIdx.x * 2;     // 512 k per row, 2 per thread
    float v0 = src[k * 64 + nc];
    float v1 = src[(k + 1) * 64 + nc];
    __bf16 h0 = (__bf16)v0, h1 = (__bf16)v1;
    WT_hi[n * 512 + k]     = h0;
    WT_hi[n * 512 + k + 1] = h1;
    WT_lo[n * 512 + k]     = (__bf16)(v0 - (float)h0);
    WT_lo[n * 512 + k + 1] = (__bf16)(v1 - (float)h1);
}

// ---------------------------------------------------------------------------
// K1: fused projection GEMM [8192,512] x [512,256] via MFMA.
//   cols   0..63 : q  (split bf16, accurate)  -> qb (bf16)
//   cols  64..127: k  (plain bf16)            -> kb
//   cols 128..191: v  (plain bf16)            -> vb
//   cols 192..255: qE (split bf16, accurate)  -> qE (f32)
// 256 blocks x 256 thr; wave (rt,ns): rows rt*16, ntiles ns,ns+2,...
// ---------------------------------------------------------------------------
__global__ __launch_bounds__(256) void proj_kernel(
        const float* __restrict__ x,
        const __bf16* __restrict__ WT_hi, const __bf16* __restrict__ WT_lo,
        __bf16* __restrict__ qb, __bf16* __restrict__ kb,
        __bf16* __restrict__ vb, float* __restrict__ qE) {
    int tid = threadIdx.x;
    int lane = tid & 63, w = tid >> 6;
    int rt = w >> 1, ns = w & 1;
    int l15 = lane & 15, kg = lane >> 4;
    int rowA = blockIdx.x * 32 + rt * 16 + l15;
    const float* xrow = x + (size_t)rowA * 512;

    f32x4 acc[8];
#pragma unroll
    for (int i = 0; i < 8; i++) acc[i] = zero4();

    for (int ks = 0; ks < 16; ks++) {
        int k0 = ks * 32 + kg * 8;
        f32x4 a0 = *(const f32x4*)(xrow + k0);
        f32x4 a1 = *(const f32x4*)(xrow + k0 + 4);
        bf16x8 xh, xl;
#pragma unroll
        for (int e = 0; e < 4; e++) {
            float v = a0[e]; __bf16 h = (__bf16)v;
            xh[e] = h; xl[e] = (__bf16)(v - (float)h);
            v = a1[e]; h = (__bf16)v;
            xh[4 + e] = h; xl[4 + e] = (__bf16)(v - (float)h);
        }
#pragma unroll
        for (int i = 0; i < 8; i++) {
            int nt = ns + 2 * i;
            const __bf16* bp = WT_hi + (size_t)(nt * 16 + l15) * 512 + k0;
            bf16x8 bh = *(const bf16x8*)bp;
            acc[i] = MFMA16(xh, bh, acc[i]);
            if (nt < 4 || nt >= 12) {   // accurate (split) columns: q, qE
                bf16x8 bl = *(const bf16x8*)(WT_lo + (size_t)(nt * 16 + l15) * 512 + k0);
                acc[i] = MFMA16(xh, bl, acc[i]);
                acc[i] = MFMA16(xl, bh, acc[i]);
            }
        }
    }
    // epilogue: C/D layout col=lane&15, row=(lane>>4)*4+r
    int rowO = blockIdx.x * 32 + rt * 16 + kg * 4;
#pragma unroll
    for (int i = 0; i < 8; i++) {
        int nt = ns + 2 * i;
        int col = nt * 16 + l15;
#pragma unroll
        for (int r = 0; r < 4; r++) {
            float v = acc[i][r];
            int row = rowO + r;
            if (nt < 4) {
                qb[row * 64 + col] = (__bf16)v;
            } else if (nt < 12) {
                int c2 = col - 64;
                if (c2 < 64) kb[row * 64 + c2] = (__bf16)v;
                else         vb[row * 64 + (c2 - 64)] = (__bf16)v;
            } else {
                qE[row * 64 + (col - 192)] = v;
            }
        }
    }
}

// ---------------------------------------------------------------------------
// K3: causal flash attention with rel-pos bias.
// grid 256: b = blk&7 (XCD locality), tq = blk>>3. 128 thr (2 waves x 16 rows)
// ---------------------------------------------------------------------------
__global__ __launch_bounds__(128) void attn_kernel(
        const __bf16* __restrict__ qb, const __bf16* __restrict__ kb,
        const __bf16* __restrict__ vb, const float* __restrict__ qE,
        float* __restrict__ out) {
    __shared__ __bf16 Klds[64][72];   // K tile [s][d], stride 72 (2-way max)
    __shared__ __bf16 Vt[64][72];     // V^T tile [d][s]
    __shared__ __bf16 Plds[2][16][72];// per-wave P [qrow][s]
    __shared__ float  qEs[32][50];    // bias tile

    int tid = threadIdx.x;
    int b = blockIdx.x & 7, tq = blockIdx.x >> 3;
    int bT = b * 1024;
    int lane = tid & 63, w = tid >> 6;
    int l15 = lane & 15, kg = lane >> 4;

    // stage bias tile (rows tq*32..+31, j 0..49)
    for (int idx = tid; idx < 32 * 50; idx += 128) {
        int r = idx / 50, j = idx - r * 50;
        qEs[r][j] = qE[(bT + tq * 32 + r) * 64 + j];
    }

    // Q fragments (A-operand: row = lane&15, k = (lane>>4)*8 + e)
    int qrow = bT + tq * 32 + w * 16 + l15;
    bf16x8 qf0 = *(const bf16x8*)(qb + (size_t)qrow * 64 + kg * 8);
    bf16x8 qf1 = *(const bf16x8*)(qb + (size_t)qrow * 64 + 32 + kg * 8);

    f32x4 O[4]; float m[4], ll[4];
#pragma unroll
    for (int i = 0; i < 4; i++) { O[i] = zero4(); m[i] = -1e30f; ll[i] = 0.f; }

    int ntiles = (tq >> 1) + 1;
    for (int it = 0; it < ntiles; it++) {
        int sb = it * 64;
        __syncthreads();   // previous tile's LDS reads complete
        {   // stage K [64][64] bf16, coalesced b128 -> b128
            int row = tid >> 1, half = tid & 1;
            const __bf16* kp = kb + (size_t)(bT + sb + row) * 64 + half * 32;
#pragma unroll
            for (int i = 0; i < 4; i++)
                *(bf16x8*)&Klds[row][half * 32 + i * 8] = *(const bf16x8*)(kp + i * 8);
        }
        {   // stage V transposed: thread covers 2 s-rows x 16 d, packed b32 writes
            int sp = (tid & 31) * 2, dseg = (tid >> 5) * 16;
            const __bf16* vp0 = vb + (size_t)(bT + sb + sp) * 64 + dseg;
            const __bf16* vp1 = vp0 + 64;
            bf16x8 r0a = *(const bf16x8*)vp0, r0b = *(const bf16x8*)(vp0 + 8);
            bf16x8 r1a = *(const bf16x8*)vp1, r1b = *(const bf16x8*)(vp1 + 8);
#pragma unroll
            for (int i = 0; i < 8; i++) {
                unsigned int p0 = (unsigned int)bf16_bits(r0a[i]) |
                                  ((unsigned int)bf16_bits(r1a[i]) << 16);
                *(unsigned int*)&Vt[dseg + i][sp] = p0;
                unsigned int p1 = (unsigned int)bf16_bits(r0b[i]) |
                                  ((unsigned int)bf16_bits(r1b[i]) << 16);
                *(unsigned int*)&Vt[dseg + 8 + i][sp] = p1;
            }
        }
        __syncthreads();

        // QK^T: S[16q x 64s] per wave
        f32x4 s[4];
#pragma unroll
        for (int ct = 0; ct < 4; ct++) {
            bf16x8 kf0 = *(const bf16x8*)&Klds[ct * 16 + l15][kg * 8];
            bf16x8 kf1 = *(const bf16x8*)&Klds[ct * 16 + l15][32 + kg * 8];
            f32x4 z = zero4();
            z = MFMA16(qf0, kf0, z);
            s[ct] = MFMA16(qf1, kf1, z);
        }

        // online softmax (rows = kg*4 + r, cols = ct*16 + l15)
        float p[4][4];
        int trow0 = w * 16 + kg * 4;
#pragma unroll
        for (int r = 0; r < 4; r++) {
            int trow = trow0 + r;
            int tg = tq * 32 + trow;
            float mx = -1e30f;
#pragma unroll
            for (int ct = 0; ct < 4; ct++) {
                int sg = sb + ct * 16 + l15;
                int d = sg - tg;
                int idxj = (d < -49 ? -49 : d);
                idxj = (idxj > 0 ? 0 : idxj) + 49;   // clip(d,-49,0)+49 in [0,49]
                float lg = s[ct][r] * 0.125f + qEs[trow][idxj];
                if (d > 0) lg = -1e30f;              // causal mask
                p[r][ct] = lg;
                mx = fmaxf(mx, lg);
            }
            mx = fmaxf(mx, __shfl_xor(mx, 1));
            mx = fmaxf(mx, __shfl_xor(mx, 2));
            mx = fmaxf(mx, __shfl_xor(mx, 4));
            mx = fmaxf(mx, __shfl_xor(mx, 8));
            float mnew = fmaxf(m[r], mx);
            float alpha = __expf(m[r] - mnew);
            m[r] = mnew;
            float ps = 0.f;
#pragma unroll
            for (int ct = 0; ct < 4; ct++) {
                float pv = __expf(p[r][ct] - mnew);
                p[r][ct] = pv;
                ps += pv;
            }
            ps += __shfl_xor(ps, 1);
            ps += __shfl_xor(ps, 2);
            ps += __shfl_xor(ps, 4);
            ps += __shfl_xor(ps, 8);
            ll[r] = ll[r] * alpha + ps;
#pragma unroll
            for (int dt = 0; dt < 4; dt++) O[dt][r] *= alpha;
        }

        // write P (per-wave buffer)
#pragma unroll
        for (int r = 0; r < 4; r++) {
            int prow = kg * 4 + r;
#pragma unroll
            for (int ct = 0; ct < 4; ct++)
                Plds[w][prow][ct * 16 + l15] = (__bf16)p[r][ct];
        }
        __syncthreads();   // P visible (cross-lane), V/K reads fenced

        // PV: O[16q x 64d] += P[16 x 64] * V[64 x 64]
#pragma unroll
        for (int ks = 0; ks < 2; ks++) {
            bf16x8 af = *(const bf16x8*)&Plds[w][l15][ks * 32 + kg * 8];
#pragma unroll
            for (int dt = 0; dt < 4; dt++) {
                bf16x8 vf = *(const bf16x8*)&Vt[dt * 16 + l15][ks * 32 + kg * 8];
                O[dt] = MFMA16(af, vf, O[dt]);
            }
        }
    }

    // epilogue
    int rowg = bT + tq * 32 + w * 16 + kg * 4;
#pragma unroll
    for (int dt = 0; dt < 4; dt++) {
#pragma unroll
        for (int r = 0; r < 4; r++) {
            out[(size_t)(rowg + r) * 64 + dt * 16 + l15] = O[dt][r] / ll[r];
        }
    }
}

// ---------------------------------------------------------------------------
extern "C" void kernel_launch(void* const* d_in, const int* in_sizes, int n_in,
                              void* d_out, int out_size, void* d_ws, size_t ws_size,
                              hipStream_t stream) {
    const float* x   = (const float*)d_in[0];
    const float* Wq  = (const float*)d_in[1];
    const float* Wk  = (const float*)d_in[2];
    const float* Wv  = (const float*)d_in[3];
    const float* rpe = (const float*)d_in[4];

    char* ws = (char*)d_ws;
    float*  G     = (float*)(ws);                          // 128 KB
    __bf16* WT_hi = (__bf16*)(ws + (128 << 10));           // 256 KB
    __bf16* WT_lo = (__bf16*)(ws + (384 << 10));           // 256 KB
    __bf16* qbuf  = (__bf16*)(ws + (640 << 10));           // 1 MB
    __bf16* kbuf  = (__bf16*)(ws + (1664 << 10));          // 1 MB
    __bf16* vbuf  = (__bf16*)(ws + (2688 << 10));          // 1 MB
    float*  qE    = (float*)(ws + (3712 << 10));           // 2 MB
    float*  outp  = (float*)d_out;

    hipLaunchKernelGGL(g_build_kernel,  dim3(128), dim3(256), 0, stream, Wq, rpe, G);
    hipLaunchKernelGGL(wt_build_kernel, dim3(256), dim3(256), 0, stream,
                       Wq, Wk, Wv, G, WT_hi, WT_lo);
    hipLaunchKernelGGL(proj_kernel,     dim3(256), dim3(256), 0, stream,
                       x, WT_hi, WT_lo, qbuf, kbuf, vbuf, qE);
    hipLaunchKernelGGL(attn_kernel,     dim3(256), dim3(128), 0, stream,
                       qbuf, kbuf, vbuf, qE, outp);
}

// Round 2
// 126.528 us; speedup vs baseline: 1.1469x; 1.1469x over previous
//
#include <hip/hip_runtime.h>
#include <hip/hip_bf16.h>

typedef __bf16 bf16x8 __attribute__((ext_vector_type(8)));
typedef float  f32x4  __attribute__((ext_vector_type(4)));

#define MFMA16(a, b, c) __builtin_amdgcn_mfma_f32_16x16x32_bf16(a, b, c, 0, 0, 0)

static __device__ __forceinline__ unsigned short bf16_bits(__bf16 v) {
    union { __bf16 b; unsigned short u; } x; x.b = v; return x.u;
}
static __device__ __forceinline__ f32x4 zero4() {
    f32x4 z = {0.f, 0.f, 0.f, 0.f}; return z;
}

// ---------------------------------------------------------------------------
// K0: WT_hi/lo[n][k] = split(bf16) of augmented-W^T; n: [Wq|Wk|Wv|G] cols.
// G[c][j] = dot(Wq[c,:], rpe[j,:]) computed inline for n>=192.
// ---------------------------------------------------------------------------
__global__ void wt_build_kernel(const float* __restrict__ Wq,
                                const float* __restrict__ Wk,
                                const float* __restrict__ Wv,
                                const float* __restrict__ rpe,
                                __bf16* __restrict__ WT_hi,
                                __bf16* __restrict__ WT_lo) {
    int n = blockIdx.x;          // 0..255
    int k = threadIdx.x * 2;     // 512 k per row, 2 per thread
    float v0, v1;
    if (n < 192) {
        const float* src; int nc;
        if (n < 64)       { src = Wq; nc = n; }
        else if (n < 128) { src = Wk; nc = n - 64; }
        else              { src = Wv; nc = n - 128; }
        v0 = src[k * 64 + nc];
        v1 = src[(k + 1) * 64 + nc];
    } else {
        int nc = n - 192;        // rel-pos column j (only j<50 consumed later)
        const f32x4* rp = (const f32x4*)(rpe + nc * 64);
        const f32x4* w0 = (const f32x4*)(Wq + k * 64);
        const f32x4* w1 = (const f32x4*)(Wq + (k + 1) * 64);
        float a0 = 0.f, a1 = 0.f;
#pragma unroll
        for (int i = 0; i < 16; i++) {
            f32x4 r = rp[i], x0 = w0[i], x1 = w1[i];
            a0 += x0.x * r.x + x0.y * r.y + x0.z * r.z + x0.w * r.w;
            a1 += x1.x * r.x + x1.y * r.y + x1.z * r.z + x1.w * r.w;
        }
        v0 = a0; v1 = a1;
    }
    __bf16 h0 = (__bf16)v0, h1 = (__bf16)v1;
    WT_hi[n * 512 + k]     = h0;
    WT_hi[n * 512 + k + 1] = h1;
    WT_lo[n * 512 + k]     = (__bf16)(v0 - (float)h0);
    WT_lo[n * 512 + k + 1] = (__bf16)(v1 - (float)h1);
}

// ---------------------------------------------------------------------------
// K1: fused projection GEMM [8192,512] x [512,256] via MFMA.
//   cols   0..63 : q  (split bf16, accurate)  -> qb (bf16)
//   cols  64..127: k  (plain bf16)            -> kb
//   cols 128..191: v  (plain bf16)            -> vb
//   cols 192..255: qE (split bf16, accurate)  -> qE (f32)
// grid 512 x 256 thr: block = 16 rows; wave c owns nt = c+4i (i=0..3):
// i==0 and i==3 are the accurate (3-MFMA split) tiles -> balanced waves.
// ---------------------------------------------------------------------------
__global__ __launch_bounds__(256) void proj_kernel(
        const float* __restrict__ x,
        const __bf16* __restrict__ WT_hi, const __bf16* __restrict__ WT_lo,
        __bf16* __restrict__ qb, __bf16* __restrict__ kb,
        __bf16* __restrict__ vb, float* __restrict__ qE) {
    int tid = threadIdx.x;
    int lane = tid & 63, c = tid >> 6;          // c = wave = col-group 0..3
    int l15 = lane & 15, kg = lane >> 4;
    int rowA = blockIdx.x * 16 + l15;
    const float* xrow = x + (size_t)rowA * 512;

    f32x4 acc[4];
#pragma unroll
    for (int i = 0; i < 4; i++) acc[i] = zero4();

#pragma unroll
    for (int ks = 0; ks < 16; ks++) {
        int k0 = ks * 32 + kg * 8;
        f32x4 a0 = *(const f32x4*)(xrow + k0);
        f32x4 a1 = *(const f32x4*)(xrow + k0 + 4);
        bf16x8 xh, xl;
#pragma unroll
        for (int e = 0; e < 4; e++) {
            float v = a0[e]; __bf16 h = (__bf16)v;
            xh[e] = h; xl[e] = (__bf16)(v - (float)h);
            v = a1[e]; h = (__bf16)v;
            xh[4 + e] = h; xl[4 + e] = (__bf16)(v - (float)h);
        }
#pragma unroll
        for (int i = 0; i < 4; i++) {
            int nt = c + 4 * i;
            const __bf16* bp = WT_hi + (size_t)(nt * 16 + l15) * 512 + k0;
            bf16x8 bh = *(const bf16x8*)bp;
            acc[i] = MFMA16(xh, bh, acc[i]);
            if (i == 0 || i == 3) {   // accurate (split) columns: q, qE
                bf16x8 bl = *(const bf16x8*)(WT_lo + (size_t)(nt * 16 + l15) * 512 + k0);
                acc[i] = MFMA16(xh, bl, acc[i]);
                acc[i] = MFMA16(xl, bh, acc[i]);
            }
        }
    }
    // epilogue: C/D layout col=lane&15, row=(lane>>4)*4+r
    int rowO = blockIdx.x * 16 + kg * 4;
#pragma unroll
    for (int i = 0; i < 4; i++) {
        int col = (c + 4 * i) * 16 + l15;       // global col 0..255
        int cc = col & 63;
#pragma unroll
        for (int r = 0; r < 4; r++) {
            float v = acc[i][r];
            int row = rowO + r;
            if (i == 0)      qb[row * 64 + cc] = (__bf16)v;
            else if (i == 1) kb[row * 64 + cc] = (__bf16)v;
            else if (i == 2) vb[row * 64 + cc] = (__bf16)v;
            else             qE[row * 64 + cc] = v;
        }
    }
}

// ---------------------------------------------------------------------------
// K2: causal flash attention with rel-pos bias.
// grid 256: b = blk&7 (XCD locality), tq = blk>>3 (32 q-rows each).
// 256 thr = 4 waves: rh = w>>1 (which 16 q-rows), kvq = w&1 (even/odd kv-tiles).
// Online-softmax partials merged across kvq at the end.
// ---------------------------------------------------------------------------
__global__ __launch_bounds__(256) void attn_kernel(
        const __bf16* __restrict__ qb, const __bf16* __restrict__ kb,
        const __bf16* __restrict__ vb, const float* __restrict__ qE,
        float* __restrict__ out) {
    __shared__ __bf16 Klds[2][64][72];   // per-kvq K tile [s][d]
    __shared__ __bf16 Vt[2][64][72];     // per-kvq V^T tile [d][s]
    __shared__ __bf16 Plds[4][16][72];   // per-wave P [qrow][s]
    __shared__ float  qEs[32][50];       // bias tile
    __shared__ float  Oc[2][16][66];     // combine: kvq1 partial O per rh
    __shared__ float  mc[2][16], lc[2][16];

    int tid = threadIdx.x;
    int b = blockIdx.x & 7, tq = blockIdx.x >> 3;
    int bT = b * 1024;
    int lane = tid & 63, w = tid >> 6;
    int rh = w >> 1, kvq = w & 1;
    int l15 = lane & 15, kg = lane >> 4;
    int ptid = rh * 64 + lane;           // 0..127 within kvq staging group

    // stage bias tile (rows tq*32..+31, j 0..49)
    for (int idx = tid; idx < 32 * 50; idx += 256) {
        int r = idx / 50, j = idx - r * 50;
        qEs[r][j] = qE[(bT + tq * 32 + r) * 64 + j];
    }

    // Q fragments (A-operand: row = lane&15, k = (lane>>4)*8 + e)
    int qrow = bT + tq * 32 + rh * 16 + l15;
    bf16x8 qf0 = *(const bf16x8*)(qb + (size_t)qrow * 64 + kg * 8);
    bf16x8 qf1 = *(const bf16x8*)(qb + (size_t)qrow * 64 + 32 + kg * 8);

    f32x4 O[4]; float m[4], ll[4];
#pragma unroll
    for (int i = 0; i < 4; i++) { O[i] = zero4(); m[i] = -1e30f; ll[i] = 0.f; }

    int ntiles = (tq >> 1) + 1;          // kv tiles of 64 covering causal range
    int R = (ntiles + 1) >> 1;           // rounds with 2-way kv split
    for (int rr = 0; rr < R; rr++) {
        int it = rr * 2 + kvq;
        int active = (it < ntiles);
        int sb = it * 64;
        __syncthreads();   // previous round's LDS reads complete
        if (active) {
            {   // stage K [64][64] bf16 (128 threads of this kvq group)
                int row = ptid >> 1, half = ptid & 1;
                const __bf16* kp = kb + (size_t)(bT + sb + row) * 64 + half * 32;
#pragma unroll
                for (int i = 0; i < 4; i++)
                    *(bf16x8*)&Klds[kvq][row][half * 32 + i * 8] =
                        *(const bf16x8*)(kp + i * 8);
            }
            {   // stage V transposed: 2 s-rows x 16 d per thread, packed b32
                int sp = (ptid & 31) * 2, dseg = (ptid >> 5) * 16;
                const __bf16* vp0 = vb + (size_t)(bT + sb + sp) * 64 + dseg;
                const __bf16* vp1 = vp0 + 64;
                bf16x8 r0a = *(const bf16x8*)vp0, r0b = *(const bf16x8*)(vp0 + 8);
                bf16x8 r1a = *(const bf16x8*)vp1, r1b = *(const bf16x8*)(vp1 + 8);
#pragma unroll
                for (int i = 0; i < 8; i++) {
                    unsigned int p0 = (unsigned int)bf16_bits(r0a[i]) |
                                      ((unsigned int)bf16_bits(r1a[i]) << 16);
                    *(unsigned int*)&Vt[kvq][dseg + i][sp] = p0;
                    unsigned int p1 = (unsigned int)bf16_bits(r0b[i]) |
                                      ((unsigned int)bf16_bits(r1b[i]) << 16);
                    *(unsigned int*)&Vt[kvq][dseg + 8 + i][sp] = p1;
                }
            }
        }
        __syncthreads();
        if (!active) continue;

        // QK^T: S[16q x 64s] per wave
        f32x4 s[4];
#pragma unroll
        for (int ct = 0; ct < 4; ct++) {
            bf16x8 kf0 = *(const bf16x8*)&Klds[kvq][ct * 16 + l15][kg * 8];
            bf16x8 kf1 = *(const bf16x8*)&Klds[kvq][ct * 16 + l15][32 + kg * 8];
            f32x4 z = zero4();
            z = MFMA16(qf0, kf0, z);
            s[ct] = MFMA16(qf1, kf1, z);
        }

        // online softmax (rows = kg*4 + r, cols = ct*16 + l15)
        float p[4][4];
        int trow0 = rh * 16 + kg * 4;
#pragma unroll
        for (int r = 0; r < 4; r++) {
            int trow = trow0 + r;
            int tg = tq * 32 + trow;
            float mx = -1e30f;
#pragma unroll
            for (int ct = 0; ct < 4; ct++) {
                int sg = sb + ct * 16 + l15;
                int d = sg - tg;
                int idxj = (d < -49 ? -49 : d);
                idxj = (idxj > 0 ? 0 : idxj) + 49;   // clip(d,-49,0)+49
                float lg = s[ct][r] * 0.125f + qEs[trow][idxj];
                if (d > 0) lg = -1e30f;              // causal mask
                p[r][ct] = lg;
                mx = fmaxf(mx, lg);
            }
            mx = fmaxf(mx, __shfl_xor(mx, 1));
            mx = fmaxf(mx, __shfl_xor(mx, 2));
            mx = fmaxf(mx, __shfl_xor(mx, 4));
            mx = fmaxf(mx, __shfl_xor(mx, 8));
            float mnew = fmaxf(m[r], mx);
            float alpha = __expf(m[r] - mnew);
            m[r] = mnew;
            float ps = 0.f;
#pragma unroll
            for (int ct = 0; ct < 4; ct++) {
                float pv = __expf(p[r][ct] - mnew);
                p[r][ct] = pv;
                ps += pv;
            }
            ps += __shfl_xor(ps, 1);
            ps += __shfl_xor(ps, 2);
            ps += __shfl_xor(ps, 4);
            ps += __shfl_xor(ps, 8);
            ll[r] = ll[r] * alpha + ps;
#pragma unroll
            for (int dt = 0; dt < 4; dt++) O[dt][r] *= alpha;
        }

        // write P (per-wave buffer; same-wave read -> no barrier needed)
#pragma unroll
        for (int r = 0; r < 4; r++) {
            int prow = kg * 4 + r;
#pragma unroll
            for (int ct = 0; ct < 4; ct++)
                Plds[w][prow][ct * 16 + l15] = (__bf16)p[r][ct];
        }

        // PV: O[16q x 64d] += P[16 x 64] * V[64 x 64]
#pragma unroll
        for (int ks = 0; ks < 2; ks++) {
            bf16x8 af = *(const bf16x8*)&Plds[w][l15][ks * 32 + kg * 8];
#pragma unroll
            for (int dt = 0; dt < 4; dt++) {
                bf16x8 vf = *(const bf16x8*)&Vt[kvq][dt * 16 + l15][ks * 32 + kg * 8];
                O[dt] = MFMA16(af, vf, O[dt]);
            }
        }
    }

    // merge the two kv partials per row-half, then write out
    __syncthreads();
    if (kvq == 1) {
#pragma unroll
        for (int r = 0; r < 4; r++) {
            int row = kg * 4 + r;
            if (l15 == 0) { mc[rh][row] = m[r]; lc[rh][row] = ll[r]; }
#pragma unroll
            for (int dt = 0; dt < 4; dt++)
                Oc[rh][row][dt * 16 + l15] = O[dt][r];
        }
    }
    __syncthreads();
    if (kvq == 0) {
        int rowg = bT + tq * 32 + rh * 16 + kg * 4;
#pragma unroll
        for (int r = 0; r < 4; r++) {
            int row = kg * 4 + r;
            float mB = mc[rh][row], lB = lc[rh][row];
            float ms = fmaxf(m[r], mB);
            float a = __expf(m[r] - ms), bb = __expf(mB - ms);
            float denom = a * ll[r] + bb * lB;
            float inv = 1.0f / denom;
#pragma unroll
            for (int dt = 0; dt < 4; dt++) {
#pragma unroll
                for (int e = 0; e < 4; e++) {
                    // e indexes f32x4 lanes? No: O[dt] is f32x4 over r.
                }
            }
#pragma unroll
            for (int dt = 0; dt < 4; dt++) {
                float val = (a * O[dt][r] + bb * Oc[rh][row][dt * 16 + l15]) * inv;
                out[(size_t)(rowg + r) * 64 + dt * 16 + l15] = val;
            }
        }
    }
}

// ---------------------------------------------------------------------------
extern "C" void kernel_launch(void* const* d_in, const int* in_sizes, int n_in,
                              void* d_out, int out_size, void* d_ws, size_t ws_size,
                              hipStream_t stream) {
    const float* x   = (const float*)d_in[0];
    const float* Wq  = (const float*)d_in[1];
    const float* Wk  = (const float*)d_in[2];
    const float* Wv  = (const float*)d_in[3];
    const float* rpe = (const float*)d_in[4];

    char* ws = (char*)d_ws;
    __bf16* WT_hi = (__bf16*)(ws);                         // 256 KB
    __bf16* WT_lo = (__bf16*)(ws + (256 << 10));           // 256 KB
    __bf16* qbuf  = (__bf16*)(ws + (512 << 10));           // 1 MB
    __bf16* kbuf  = (__bf16*)(ws + (1536 << 10));          // 1 MB
    __bf16* vbuf  = (__bf16*)(ws + (2560 << 10));          // 1 MB
    float*  qE    = (float*)(ws + (3584 << 10));           // 2 MB
    float*  outp  = (float*)d_out;

    hipLaunchKernelGGL(wt_build_kernel, dim3(256), dim3(256), 0, stream,
                       Wq, Wk, Wv, rpe, WT_hi, WT_lo);
    hipLaunchKernelGGL(proj_kernel,     dim3(512), dim3(256), 0, stream,
                       x, WT_hi, WT_lo, qbuf, kbuf, vbuf, qE);
    hipLaunchKernelGGL(attn_kernel,     dim3(256), dim3(256), 0, stream,
                       qbuf, kbuf, vbuf, qE, outp);
}